// Round 16
// baseline (107.510 us; speedup 1.0000x reference)
//
#include <hip/hip_runtime.h>
#include <math.h>

// QKV attention: qkv [64][192][2048] fp32 -> out [64][64][2048] fp32
// prep: K AND V -> fragment-major 64x64 bf16 tiles:
//       chunk (R,g) -> o = (R>>5)*256 + (g>>1)*64 + (g&1)*32 + (R&31)
// attn: swapped-QK flash, bf16 MFMA 32x32x16, no-max softmax (v_exp_f32),
//       permlane32 P-transpose (volatile), VALU denominator.
//       *** NO LDS, NO BARRIERS ***: every K/V fragment is a lane-linear
//       coalesced global_load_dwordx4 (L1/L2-hot, XCD-pinned batches);
//       16 waves/CU free-run. 4 waves x 32t, 4 blocks/CU.

#define B_     64
#define CH_    64
#define T_     2048
#define TQ     128
#define SB     64
#define NIT    (T_ / SB)
#define TILE_E 4096              // elems per 64x64 bf16 tile

typedef __attribute__((ext_vector_type(8))) short short8;
typedef __attribute__((ext_vector_type(4))) float f32x4;
typedef __attribute__((ext_vector_type(16))) float f32x16;
typedef __attribute__((ext_vector_type(4))) unsigned short us4;
typedef __attribute__((ext_vector_type(8))) unsigned short us8;

static __device__ __forceinline__ unsigned short f2bf(float f) {
    union { float f; unsigned u; } v; v.f = f;
    unsigned r = v.u + 0x7FFFu + ((v.u >> 16) & 1u);   // RNE
    return (unsigned short)(r >> 16);
}

static __device__ __forceinline__ short8 ld_g16(const unsigned short* p) {
    return *(const short8*)p;                  // 16B aligned -> global_load_dwordx4
}

static __device__ __forceinline__ short8 ld_contig(const unsigned short* p) {
    return *(const short8*)p;
}

static __device__ __forceinline__ short8 ld_strided(const unsigned short* p, int stride) {
    short8 r;
#pragma unroll
    for (int j = 0; j < 8; ++j) r[j] = (short)p[j * stride];
    return r;
}

static __device__ __forceinline__ float vexp2(float x) {
#if __has_builtin(__builtin_amdgcn_exp2f)
    return __builtin_amdgcn_exp2f(x);          // single v_exp_f32
#else
    float r;
    asm volatile("v_exp_f32 %0, %1\n\ts_nop 1" : "=v"(r) : "v"(x));
    return r;
#endif
}

static __device__ __forceinline__ unsigned cvtpk(float lo, float hi) {
    unsigned r;
    asm volatile("v_cvt_pk_bf16_f32 %0, %1, %2" : "=v"(r) : "v"(lo), "v"(hi));
    return r;
}

// permlane32_swap: newA = {A.lo32, B.lo32}, newB = {A.hi32, B.hi32}
// volatile: must never be rematerialized/duplicated (swap twice = identity)
static __device__ __forceinline__ void pl32(unsigned& a, unsigned& b) {
    asm volatile("v_permlane32_swap_b32 %0, %1" : "+v"(a), "+v"(b));
}

// 16x16 composite (fallback kernel only)
static __device__ __forceinline__ void pl_swap(unsigned& a, unsigned& b) {
    asm volatile("v_permlane32_swap_b32 %0, %1" : "+v"(a), "+v"(b));
    asm volatile("v_permlane16_swap_b32 %0, %1" : "+v"(a), "+v"(b));
}

// ---------------- prep: fragment-major K and V tiles ----------------
__global__ __launch_bounds__(256) void qkv_prep(const float* __restrict__ qkv,
                                                unsigned short* __restrict__ Ktg,
                                                unsigned short* __restrict__ Vbg)
{
    __shared__ float Tl[64][65];
    const int tid = threadIdx.x;
    const int b   = blockIdx.x >> 5;
    const int st  = blockIdx.x & 31;
    const int s0  = st * 64;
    const float* Kp = qkv + (size_t)b * (3 * CH_ * T_) + (size_t)CH_ * T_;
    const float* Vp = Kp + (size_t)CH_ * T_;
    const size_t tbase = (size_t)(b * 32 + st) * TILE_E;

    // K tile [c][s_local] -> LDS fp32 (coalesced reads)
    {
        const int c = tid & 63, fq = tid >> 6;
#pragma unroll
        for (int k = 0; k < 4; ++k) {
            const int tl = 16 * fq + 4 * k;
            const float4 v = *(const float4*)(Kp + (size_t)c * T_ + s0 + tl);
            Tl[c][tl] = v.x; Tl[c][tl + 1] = v.y; Tl[c][tl + 2] = v.z; Tl[c][tl + 3] = v.w;
        }
    }

    // V: fragment-major direct permute. thread -> (R = tid>>2, chunk pair m = tid&3)
    {
        const int R = tid >> 2;
        const int m = tid & 3;
        const float* vin = Vp + (size_t)R * T_ + s0 + 16 * m;
        const float4 a0 = *(const float4*)(vin);
        const float4 a1 = *(const float4*)(vin + 4);
        const float4 a2 = *(const float4*)(vin + 8);
        const float4 a3 = *(const float4*)(vin + 12);
        us8 w0, w1;
        w0[0]=f2bf(a0.x); w0[1]=f2bf(a0.y); w0[2]=f2bf(a0.z); w0[3]=f2bf(a0.w);
        w0[4]=f2bf(a1.x); w0[5]=f2bf(a1.y); w0[6]=f2bf(a1.z); w0[7]=f2bf(a1.w);
        w1[0]=f2bf(a2.x); w1[1]=f2bf(a2.y); w1[2]=f2bf(a2.z); w1[3]=f2bf(a2.w);
        w1[4]=f2bf(a3.x); w1[5]=f2bf(a3.y); w1[6]=f2bf(a3.z); w1[7]=f2bf(a3.w);
        const int o = ((R >> 5) << 8) + (m << 6) + (R & 31);
        *(us8*)(Vbg + tbase + (size_t)o * 8)        = w0;
        *(us8*)(Vbg + tbase + (size_t)(o + 32) * 8) = w1;
    }
    __syncthreads();

    // K: fragment-major write from LDS. thread covers chunks o = tid, tid+256
    {
#pragma unroll
        for (int j2 = 0; j2 < 2; ++j2) {
            const int o = j2 * 256 + tid;
            const int R = j2 * 32 + (tid & 31);
            const int g = 2 * (tid >> 6) + ((tid >> 5) & 1);
            us8 w8;
#pragma unroll
            for (int j = 0; j < 8; ++j) w8[j] = f2bf(Tl[8 * g + j][R]);
            *(us8*)(Ktg + tbase + (size_t)o * 8) = w8;
        }
    }
}

// ---------------- main attention: no LDS, no barriers ----------------
__global__ __launch_bounds__(256, 4) void qkv_attn16(const float* __restrict__ qkv,
                                                     const unsigned short* __restrict__ Ktg,
                                                     const unsigned short* __restrict__ Vbg,
                                                     float* __restrict__ out)
{
    const int tid  = threadIdx.x;
    const int lane = tid & 63;
    const int wid  = tid >> 6;
    const int l31  = lane & 31;
    const int hi   = lane >> 5;

    int bid = blockIdx.x;
    bid = (bid & 7) * 128 + (bid >> 3);        // XCD swizzle: batches pinned per XCD
    const int b  = bid >> 4;                   // 16 t-tiles per batch
    const int t0 = (bid & 15) * TQ;
    const int tb = t0 + wid * 32;              // wave's 32 t-rows

    const float* Qp = qkv + (size_t)b * (3 * CH_ * T_);
    const int lrd = lane * 8;                  // lane-linear frag offset (elems)
    const unsigned short* kt = Ktg + (size_t)b * 32 * TILE_E + lrd;
    const unsigned short* vt = Vbg + (size_t)b * 32 * TILE_E + lrd;

    // hoisted Q B-frags (col t = l31, k = c = 16*ks + 8*hi + j), scaled 0.125*log2e
    short8 aq[4];
#pragma unroll
    for (int ks = 0; ks < 4; ++ks) {
        short8 q;
#pragma unroll
        for (int j = 0; j < 8; ++j)
            q[j] = (short)f2bf(0.180336880f *
                    Qp[(size_t)(16 * ks + 8 * hi + j) * T_ + tb + l31]);
        aq[ks] = q;
    }

    f32x16 zero16;
#pragma unroll
    for (int r = 0; r < 16; ++r) zero16[r] = 0.0f;
    f32x16 o0 = zero16, o1 = zero16;
    float dsum = 0.0f;

    for (int it = 0; it < NIT; ++it) {
        // ---- V frags for s-tile 0 (coalesced; latency hides under QK) ----
        const short8 vA0 = ld_g16(vt);               // ch0, kv0 (pba)
        const short8 vA1 = ld_g16(vt + 512);         // ch0, kv1 (pbb)
        const short8 vB0 = ld_g16(vt + 2048);        // ch1, kv0
        const short8 vB1 = ld_g16(vt + 2048 + 512);  // ch1, kv1

        // ---- QK^T (swapped): W[s][t] two 32x32 tiles, lane-linear K frags ----
        f32x16 w0 = zero16, w1 = zero16;
#pragma unroll
        for (int ks = 0; ks < 4; ++ks) {
            const short8 k0 = ld_g16(kt + ks * 512);
            const short8 k1 = ld_g16(kt + 2048 + ks * 512);
            w0 = __builtin_amdgcn_mfma_f32_32x32x16_bf16(k0, aq[ks], w0, 0, 0, 0);
            w1 = __builtin_amdgcn_mfma_f32_32x32x16_bf16(k1, aq[ks], w1, 0, 0, 0);
        }

        // ---- s-tile 0: softmax(w0) -> pack -> permlane -> PV ----
        {
            float e[16];
#pragma unroll
            for (int r = 0; r < 16; ++r) e[r] = vexp2(w0[r]);
            dsum += (((e[0] + e[1]) + (e[2] + e[3])) + ((e[4] + e[5]) + (e[6] + e[7])))
                  + (((e[8] + e[9]) + (e[10] + e[11])) + ((e[12] + e[13]) + (e[14] + e[15])));
            unsigned P0 = cvtpk(e[0], e[1]);
            unsigned P1 = cvtpk(e[2], e[3]);
            unsigned P2 = cvtpk(e[4], e[5]);
            unsigned P3 = cvtpk(e[6], e[7]);
            unsigned P4 = cvtpk(e[8], e[9]);
            unsigned P5 = cvtpk(e[10], e[11]);
            unsigned P6 = cvtpk(e[12], e[13]);
            unsigned P7 = cvtpk(e[14], e[15]);
            pl32(P0, P2);
            pl32(P1, P3);
            pl32(P4, P6);
            pl32(P5, P7);
            union { short8 s8; unsigned u[4]; } pba, pbb;
            pba.u[0] = P0; pba.u[1] = P1; pba.u[2] = P2; pba.u[3] = P3;  // s 0-15
            pbb.u[0] = P4; pbb.u[1] = P5; pbb.u[2] = P6; pbb.u[3] = P7;  // s 16-31
            o0 = __builtin_amdgcn_mfma_f32_32x32x16_bf16(vA0, pba.s8, o0, 0, 0, 0);
            o0 = __builtin_amdgcn_mfma_f32_32x32x16_bf16(vA1, pbb.s8, o0, 0, 0, 0);
            o1 = __builtin_amdgcn_mfma_f32_32x32x16_bf16(vB0, pba.s8, o1, 0, 0, 0);
            o1 = __builtin_amdgcn_mfma_f32_32x32x16_bf16(vB1, pbb.s8, o1, 0, 0, 0);
        }

        // ---- s-tile 1: V frags, softmax(w1), PV ----
        {
            const short8 vC0 = ld_g16(vt + 1024);         // ch0, kv2 (pba)
            const short8 vC1 = ld_g16(vt + 1536);         // ch0, kv3 (pbb)
            const short8 vD0 = ld_g16(vt + 2048 + 1024);  // ch1, kv2
            const short8 vD1 = ld_g16(vt + 2048 + 1536);  // ch1, kv3
            float e[16];
#pragma unroll
            for (int r = 0; r < 16; ++r) e[r] = vexp2(w1[r]);
            dsum += (((e[0] + e[1]) + (e[2] + e[3])) + ((e[4] + e[5]) + (e[6] + e[7])))
                  + (((e[8] + e[9]) + (e[10] + e[11])) + ((e[12] + e[13]) + (e[14] + e[15])));
            unsigned P0 = cvtpk(e[0], e[1]);
            unsigned P1 = cvtpk(e[2], e[3]);
            unsigned P2 = cvtpk(e[4], e[5]);
            unsigned P3 = cvtpk(e[6], e[7]);
            unsigned P4 = cvtpk(e[8], e[9]);
            unsigned P5 = cvtpk(e[10], e[11]);
            unsigned P6 = cvtpk(e[12], e[13]);
            unsigned P7 = cvtpk(e[14], e[15]);
            pl32(P0, P2);
            pl32(P1, P3);
            pl32(P4, P6);
            pl32(P5, P7);
            union { short8 s8; unsigned u[4]; } pba, pbb;
            pba.u[0] = P0; pba.u[1] = P1; pba.u[2] = P2; pba.u[3] = P3;  // s 32-47
            pbb.u[0] = P4; pbb.u[1] = P5; pbb.u[2] = P6; pbb.u[3] = P7;  // s 48-63
            o0 = __builtin_amdgcn_mfma_f32_32x32x16_bf16(vC0, pba.s8, o0, 0, 0, 0);
            o0 = __builtin_amdgcn_mfma_f32_32x32x16_bf16(vC1, pbb.s8, o0, 0, 0, 0);
            o1 = __builtin_amdgcn_mfma_f32_32x32x16_bf16(vD0, pba.s8, o1, 0, 0, 0);
            o1 = __builtin_amdgcn_mfma_f32_32x32x16_bf16(vD1, pbb.s8, o1, 0, 0, 0);
        }

        kt += TILE_E; vt += TILE_E;
    }

    // ---- denominator: lane pairs (l, l+32) share t, cover complementary s ----
    float d = dsum + __shfl_xor(dsum, 32, 64);
    const float inv = 1.0f / d;

    // ---- epilogue: D col=t=l31, row=c = 32*ch + (r&3)+8*(r>>2)+4*hi ----
    float* outp = out + (size_t)b * CH_ * T_;
#pragma unroll
    for (int r = 0; r < 16; ++r) {
        const int crow = (r & 3) + 8 * (r >> 2) + 4 * hi;
        outp[(size_t)crow * T_ + tb + l31]        = o0[r] * inv;
        outp[(size_t)(32 + crow) * T_ + tb + l31] = o1[r] * inv;
    }
}

// ---------------- fallback (round-1 kernel, used if ws too small) ----------------
__global__ __launch_bounds__(256) void qkv_attn_fb(const float* __restrict__ qkv,
                                                   float* __restrict__ out)
{
    __shared__ unsigned short Qs[CH_][68];
    __shared__ unsigned short Ksf[CH_][68];
    __shared__ unsigned short Vsf[CH_][72];
    __shared__ unsigned short Psf[4][64][18];

    const int tid  = threadIdx.x;
    const int lane = tid & 63;
    const int wid  = tid >> 6;
    const int l15  = lane & 15;
    const int h    = lane >> 4;
    const int bidx = blockIdx.x;
    const int b    = bidx >> 5;
    const int t0   = (bidx & 31) * 64;
    const int tw   = wid * 16;

    const float* Qp = qkv + (size_t)b * (3 * CH_ * T_);
    const float* Kp = Qp + CH_ * T_;
    const float* Vp = Kp + CH_ * T_;

    const int srow = tid >> 4;
    const int scol = (tid & 15) << 2;

#pragma unroll
    for (int i = 0; i < 4; ++i) {
        const int c = srow + 16 * i;
        const float4 q = *(const float4*)(Qp + (size_t)c * T_ + t0 + scol);
        us4 w; w[0] = f2bf(q.x); w[1] = f2bf(q.y); w[2] = f2bf(q.z); w[3] = f2bf(q.w);
        *(us4*)(&Qs[c][scol]) = w;
    }
    __syncthreads();

    const short8 aq0 = ld_strided(&Qs[0 + 8 * h][tw + l15], 68);
    const short8 aq1 = ld_strided(&Qs[32 + 8 * h][tw + l15], 68);

    short8 aones;
#pragma unroll
    for (int j = 0; j < 8; ++j) aones[j] = (short)0x3F80;

    f32x4 o[4];
#pragma unroll
    for (int cs = 0; cs < 4; ++cs) o[cs] = (f32x4){0.f, 0.f, 0.f, 0.f};
    float l_run = 0.0f;
    const f32x4 zero4 = {0.f, 0.f, 0.f, 0.f};

    for (int it = 0; it < 32; ++it) {
        const int s0 = it * 64;
        __syncthreads();
#pragma unroll
        for (int i = 0; i < 4; ++i) {
            const int c = srow + 16 * i;
            const float4 kv = *(const float4*)(Kp + (size_t)c * T_ + s0 + scol);
            us4 wk; wk[0] = f2bf(kv.x); wk[1] = f2bf(kv.y); wk[2] = f2bf(kv.z); wk[3] = f2bf(kv.w);
            *(us4*)(&Ksf[c][scol]) = wk;
            const float4 vv = *(const float4*)(Vp + (size_t)c * T_ + s0 + scol);
            us4 wv; wv[0] = f2bf(vv.x); wv[1] = f2bf(vv.y); wv[2] = f2bf(vv.z); wv[3] = f2bf(vv.w);
            *(us4*)(&Vsf[c][scol]) = wv;
        }
        __syncthreads();

        f32x4 w[4];
#pragma unroll
        for (int ss = 0; ss < 4; ++ss) {
            const short8 bkl = ld_strided(&Ksf[0 + 8 * h][ss * 16 + l15], 68);
            const short8 bkh = ld_strided(&Ksf[32 + 8 * h][ss * 16 + l15], 68);
            f32x4 acc = zero4;
            acc = __builtin_amdgcn_mfma_f32_16x16x32_bf16(aq0, bkl, acc, 0, 0, 0);
            acc = __builtin_amdgcn_mfma_f32_16x16x32_bf16(aq1, bkh, acc, 0, 0, 0);
            w[ss] = acc;
        }

#pragma unroll
        for (int ss = 0; ss < 4; ++ss) {
            const float e0 = __expf(0.125f * w[ss][0]);
            const float e1 = __expf(0.125f * w[ss][1]);
            const float e2 = __expf(0.125f * w[ss][2]);
            const float e3 = __expf(0.125f * w[ss][3]);
            const unsigned p01 = (unsigned)f2bf(e0) | ((unsigned)f2bf(e1) << 16);
            const unsigned p23 = (unsigned)f2bf(e2) | ((unsigned)f2bf(e3) << 16);
            const int s = ss * 16 + l15;
            *(unsigned*)(&Psf[wid][s][4 * h]) = p01;
            *(unsigned*)(&Psf[wid][s][4 * h + 2]) = p23;
        }

        const short8 pb0 = ld_strided(&Psf[wid][0 + 8 * h][l15], 18);
        const short8 pb1 = ld_strided(&Psf[wid][32 + 8 * h][l15], 18);

        f32x4 lacc = zero4;
        lacc = __builtin_amdgcn_mfma_f32_16x16x32_bf16(aones, pb0, lacc, 0, 0, 0);
        lacc = __builtin_amdgcn_mfma_f32_16x16x32_bf16(aones, pb1, lacc, 0, 0, 0);
        l_run += lacc[0];

#pragma unroll
        for (int cs = 0; cs < 4; ++cs) {
            us4 lo0 = *(const us4*)(&Vsf[cs * 16 + l15][0 + 8 * h]);
            us4 hi0 = *(const us4*)(&Vsf[cs * 16 + l15][4 + 8 * h]);
            us4 lo1 = *(const us4*)(&Vsf[cs * 16 + l15][32 + 8 * h]);
            us4 hi1 = *(const us4*)(&Vsf[cs * 16 + l15][36 + 8 * h]);
            short8 av0, av1;
            av0[0]=(short)lo0[0]; av0[1]=(short)lo0[1]; av0[2]=(short)lo0[2]; av0[3]=(short)lo0[3];
            av0[4]=(short)hi0[0]; av0[5]=(short)hi0[1]; av0[6]=(short)hi0[2]; av0[7]=(short)hi0[3];
            av1[0]=(short)lo1[0]; av1[1]=(short)lo1[1]; av1[2]=(short)lo1[2]; av1[3]=(short)lo1[3];
            av1[4]=(short)hi1[0]; av1[5]=(short)hi1[1]; av1[6]=(short)hi1[2]; av1[7]=(short)hi1[3];
            o[cs] = __builtin_amdgcn_mfma_f32_16x16x32_bf16(av0, pb0, o[cs], 0, 0, 0);
            o[cs] = __builtin_amdgcn_mfma_f32_16x16x32_bf16(av1, pb1, o[cs], 0, 0, 0);
        }
    }

    const float invd = 1.0f / l_run;
    float* outp = out + (size_t)b * CH_ * T_;
#pragma unroll
    for (int cs = 0; cs < 4; ++cs)
#pragma unroll
        for (int r = 0; r < 4; ++r)
            outp[(size_t)(cs * 16 + 4 * h + r) * T_ + t0 + tw + l15] = o[cs][r] * invd;
}

extern "C" void kernel_launch(void* const* d_in, const int* in_sizes, int n_in,
                              void* d_out, int out_size, void* d_ws, size_t ws_size,
                              hipStream_t stream) {
    const float* qkv = (const float*)d_in[0];
    float* outp = (float*)d_out;
    const size_t need = (size_t)2 * B_ * CH_ * T_ * sizeof(unsigned short); // 32 MB
    if (ws_size >= need) {
        unsigned short* Ktg = (unsigned short*)d_ws;
        unsigned short* Vbg = Ktg + (size_t)B_ * T_ * CH_;
        qkv_prep<<<dim3(B_ * 32), dim3(256), 0, stream>>>(qkv, Ktg, Vbg);
        qkv_attn16<<<dim3(B_ * (T_ / TQ)), dim3(256), 0, stream>>>(qkv, Ktg, Vbg, outp);
    } else {
        qkv_attn_fb<<<dim3(B_ * 32), dim3(256), 0, stream>>>(qkv, outp);
    }
}

// Round 17
// 93.523 us; speedup vs baseline: 1.1496x; 1.1496x over previous
//
#include <hip/hip_runtime.h>
#include <math.h>

// QKV attention: qkv [64][192][2048] fp32 -> out [64][64][2048] fp32
// prep: K AND V -> fragment-major 64x64 bf16 tiles:
//       chunk (R,g) -> o = (R>>5)*256 + (g>>1)*64 + (g&1)*32 + (R&31)
// attn: swapped-QK flash, bf16 MFMA 32x32x16, no-max softmax (v_exp_f32),
//       permlane32 P-transpose (volatile), VALU denominator.
//       TQ=256: 4 waves x 64t (two 32-col subtiles per wave) -> each K/V
//       ds_read feeds 4 MFMAs (DS per work halved vs TQ=128).
//       K/V staged in LDS lane-linear (conflict-free), dbuf, 2 blocks/CU.

#define B_     64
#define CH_    64
#define T_     2048
#define TQ     256
#define SB     64
#define NIT    (T_ / SB)
#define TILE_E 4096              // elems per 64x64 bf16 tile

typedef __attribute__((ext_vector_type(8))) short short8;
typedef __attribute__((ext_vector_type(4))) float f32x4;
typedef __attribute__((ext_vector_type(16))) float f32x16;
typedef __attribute__((ext_vector_type(4))) unsigned short us4;
typedef __attribute__((ext_vector_type(8))) unsigned short us8;

static __device__ __forceinline__ unsigned short f2bf(float f) {
    union { float f; unsigned u; } v; v.f = f;
    unsigned r = v.u + 0x7FFFu + ((v.u >> 16) & 1u);   // RNE
    return (unsigned short)(r >> 16);
}

static __device__ __forceinline__ short8 ld_contig(const unsigned short* p) {
    return *(const short8*)p;                  // 16B aligned (LDS: ds_read_b128)
}

static __device__ __forceinline__ short8 ld_strided(const unsigned short* p, int stride) {
    short8 r;
#pragma unroll
    for (int j = 0; j < 8; ++j) r[j] = (short)p[j * stride];
    return r;
}

static __device__ __forceinline__ void gl_lds16(const unsigned short* g, unsigned short* l) {
    __builtin_amdgcn_global_load_lds(
        (const __attribute__((address_space(1))) unsigned int*)g,
        (__attribute__((address_space(3))) unsigned int*)l, 16, 0, 0);
}

static __device__ __forceinline__ float vexp2(float x) {
#if __has_builtin(__builtin_amdgcn_exp2f)
    return __builtin_amdgcn_exp2f(x);          // single v_exp_f32
#else
    float r;
    asm volatile("v_exp_f32 %0, %1\n\ts_nop 1" : "=v"(r) : "v"(x));
    return r;
#endif
}

static __device__ __forceinline__ unsigned cvtpk(float lo, float hi) {
    unsigned r;
    asm volatile("v_cvt_pk_bf16_f32 %0, %1, %2" : "=v"(r) : "v"(lo), "v"(hi));
    return r;
}

// permlane32_swap: newA = {A.lo32, B.lo32}, newB = {A.hi32, B.hi32}
// volatile: must never be rematerialized/duplicated (swap twice = identity)
static __device__ __forceinline__ void pl32(unsigned& a, unsigned& b) {
    asm volatile("v_permlane32_swap_b32 %0, %1" : "+v"(a), "+v"(b));
}

// 16x16 composite (fallback kernel only)
static __device__ __forceinline__ void pl_swap(unsigned& a, unsigned& b) {
    asm volatile("v_permlane32_swap_b32 %0, %1" : "+v"(a), "+v"(b));
    asm volatile("v_permlane16_swap_b32 %0, %1" : "+v"(a), "+v"(b));
}

// softmax + in-register transpose: W(32s x 32t C-layout) -> two PV B-frags
static __device__ __forceinline__ void softmax_pack(const f32x16& w, float& dsum,
                                                    short8& pba, short8& pbb) {
    float e[16];
#pragma unroll
    for (int r = 0; r < 16; ++r) e[r] = vexp2(w[r]);
    dsum += (((e[0] + e[1]) + (e[2] + e[3])) + ((e[4] + e[5]) + (e[6] + e[7])))
          + (((e[8] + e[9]) + (e[10] + e[11])) + ((e[12] + e[13]) + (e[14] + e[15])));
    unsigned P0 = cvtpk(e[0], e[1]);
    unsigned P1 = cvtpk(e[2], e[3]);
    unsigned P2 = cvtpk(e[4], e[5]);
    unsigned P3 = cvtpk(e[6], e[7]);
    unsigned P4 = cvtpk(e[8], e[9]);
    unsigned P5 = cvtpk(e[10], e[11]);
    unsigned P6 = cvtpk(e[12], e[13]);
    unsigned P7 = cvtpk(e[14], e[15]);
    pl32(P0, P2);
    pl32(P1, P3);
    pl32(P4, P6);
    pl32(P5, P7);
    union { short8 s8; unsigned u[4]; } a, b;
    a.u[0] = P0; a.u[1] = P1; a.u[2] = P2; a.u[3] = P3;   // s chunk lo (16)
    b.u[0] = P4; b.u[1] = P5; b.u[2] = P6; b.u[3] = P7;   // s chunk hi (16)
    pba = a.s8; pbb = b.s8;
}

// ---------------- prep: fragment-major K and V tiles ----------------
__global__ __launch_bounds__(256) void qkv_prep(const float* __restrict__ qkv,
                                                unsigned short* __restrict__ Ktg,
                                                unsigned short* __restrict__ Vbg)
{
    __shared__ float Tl[64][65];
    const int tid = threadIdx.x;
    const int b   = blockIdx.x >> 5;
    const int st  = blockIdx.x & 31;
    const int s0  = st * 64;
    const float* Kp = qkv + (size_t)b * (3 * CH_ * T_) + (size_t)CH_ * T_;
    const float* Vp = Kp + (size_t)CH_ * T_;
    const size_t tbase = (size_t)(b * 32 + st) * TILE_E;

    // K tile [c][s_local] -> LDS fp32 (coalesced reads)
    {
        const int c = tid & 63, fq = tid >> 6;
#pragma unroll
        for (int k = 0; k < 4; ++k) {
            const int tl = 16 * fq + 4 * k;
            const float4 v = *(const float4*)(Kp + (size_t)c * T_ + s0 + tl);
            Tl[c][tl] = v.x; Tl[c][tl + 1] = v.y; Tl[c][tl + 2] = v.z; Tl[c][tl + 3] = v.w;
        }
    }

    // V: fragment-major direct permute. thread -> (R = tid>>2, chunk pair m = tid&3)
    {
        const int R = tid >> 2;
        const int m = tid & 3;
        const float* vin = Vp + (size_t)R * T_ + s0 + 16 * m;
        const float4 a0 = *(const float4*)(vin);
        const float4 a1 = *(const float4*)(vin + 4);
        const float4 a2 = *(const float4*)(vin + 8);
        const float4 a3 = *(const float4*)(vin + 12);
        us8 w0, w1;
        w0[0]=f2bf(a0.x); w0[1]=f2bf(a0.y); w0[2]=f2bf(a0.z); w0[3]=f2bf(a0.w);
        w0[4]=f2bf(a1.x); w0[5]=f2bf(a1.y); w0[6]=f2bf(a1.z); w0[7]=f2bf(a1.w);
        w1[0]=f2bf(a2.x); w1[1]=f2bf(a2.y); w1[2]=f2bf(a2.z); w1[3]=f2bf(a2.w);
        w1[4]=f2bf(a3.x); w1[5]=f2bf(a3.y); w1[6]=f2bf(a3.z); w1[7]=f2bf(a3.w);
        const int o = ((R >> 5) << 8) + (m << 6) + (R & 31);
        *(us8*)(Vbg + tbase + (size_t)o * 8)        = w0;
        *(us8*)(Vbg + tbase + (size_t)(o + 32) * 8) = w1;
    }
    __syncthreads();

    // K: fragment-major write from LDS. thread covers chunks o = tid, tid+256
    {
#pragma unroll
        for (int j2 = 0; j2 < 2; ++j2) {
            const int o = j2 * 256 + tid;
            const int R = j2 * 32 + (tid & 31);
            const int g = 2 * (tid >> 6) + ((tid >> 5) & 1);
            us8 w8;
#pragma unroll
            for (int j = 0; j < 8; ++j) w8[j] = f2bf(Tl[8 * g + j][R]);
            *(us8*)(Ktg + tbase + (size_t)o * 8) = w8;
        }
    }
}

// ---------------- main attention: TQ=256, 4 waves x 64t ----------------
__global__ __launch_bounds__(256, 2) void qkv_attn17(const float* __restrict__ qkv,
                                                     const unsigned short* __restrict__ Ktg,
                                                     const unsigned short* __restrict__ Vbg,
                                                     float* __restrict__ out)
{
    __shared__ unsigned short Ks[2][TILE_E];
    __shared__ unsigned short Vs[2][TILE_E];

    const int tid  = threadIdx.x;
    const int lane = tid & 63;
    const int wid  = tid >> 6;
    const int l31  = lane & 31;
    const int hi   = lane >> 5;

    int bid = blockIdx.x;
    bid = (bid & 7) * 64 + (bid >> 3);         // XCD swizzle (512 = 8*64, bijective)
    const int b  = bid >> 3;                   // 8 t-tiles per batch
    const int t0 = (bid & 7) * TQ;
    const int tb = t0 + wid * 64;              // wave's 64 t-rows (two 32-col subtiles)

    const float* Qp = qkv + (size_t)b * (3 * CH_ * T_);
    const unsigned short* Ktb = Ktg + (size_t)b * 32 * TILE_E;
    const unsigned short* Vtb = Vbg + (size_t)b * 32 * TILE_E;

    // staging: lane-linear fragment-major chunks (chunk index = tid / tid+256)
    const unsigned short* ksrc = Ktb + (size_t)tid * 8;
    const unsigned short* vsrc = Vtb + (size_t)tid * 8;
    const int lrd = lane * 8;                  // lane-linear frag read offset
    const int sofs = wid * 512;                // per-wave staging dest offset

    // hoisted Q B-frags: ts in {0,1}, col t = tb + 32*ts + l31, k = c = 16ks+8hi+j
    short8 aq0[4], aq1[4];
#pragma unroll
    for (int ks = 0; ks < 4; ++ks) {
        short8 q0, q1;
#pragma unroll
        for (int j = 0; j < 8; ++j) {
            const float* qrow = Qp + (size_t)(16 * ks + 8 * hi + j) * T_ + tb + l31;
            q0[j] = (short)f2bf(0.180336880f * qrow[0]);
            q1[j] = (short)f2bf(0.180336880f * qrow[32]);
        }
        aq0[ks] = q0; aq1[ks] = q1;
    }

    f32x16 zero16;
#pragma unroll
    for (int r = 0; r < 16; ++r) zero16[r] = 0.0f;
    f32x16 o00 = zero16, o01 = zero16, o10 = zero16, o11 = zero16;
    float dsum0 = 0.0f, dsum1 = 0.0f;

    // prologue: stage tile 0 into buf 0 (K + V, lane-linear)
    gl_lds16(ksrc,        &Ks[0][sofs]);
    gl_lds16(ksrc + 2048, &Ks[0][2048 + sofs]);
    gl_lds16(vsrc,        &Vs[0][sofs]);
    gl_lds16(vsrc + 2048, &Vs[0][2048 + sofs]);

    for (int it = 0; it < NIT; ++it) {
        __syncthreads();                       // tile staged, prev reads done
        const int buf = it & 1;
        if (it + 1 < NIT) {
            const unsigned short* kn = ksrc + (size_t)(it + 1) * TILE_E;
            const unsigned short* vn = vsrc + (size_t)(it + 1) * TILE_E;
            const int bo = (buf ^ 1) * TILE_E;
            gl_lds16(kn,        &Ks[0][bo + sofs]);
            gl_lds16(kn + 2048, &Ks[0][bo + 2048 + sofs]);
            gl_lds16(vn,        &Vs[0][bo + sofs]);
            gl_lds16(vn + 2048, &Vs[0][bo + 2048 + sofs]);
        }
        const unsigned short* kb = &Ks[buf][0];
        const unsigned short* vb = &Vs[buf][0];

        __builtin_amdgcn_s_setprio(1);

#pragma unroll
        for (int st = 0; st < 2; ++st) {
            // ---- QK^T: one K frag feeds BOTH t-subtiles (4 MFMAs per read pair) ----
            f32x16 wA = zero16, wB = zero16;
#pragma unroll
            for (int ks = 0; ks < 4; ++ks) {
                const short8 k0 = ld_contig(kb + st * 2048 + ks * 512 + lrd);
                wA = __builtin_amdgcn_mfma_f32_32x32x16_bf16(k0, aq0[ks], wA, 0, 0, 0);
                wB = __builtin_amdgcn_mfma_f32_32x32x16_bf16(k0, aq1[ks], wB, 0, 0, 0);
            }

            // ---- V frags (shared across ts) ----
            const short8 v00 = ld_contig(vb + (2 * st) * 512 + lrd);            // ch0,pba
            const short8 v01 = ld_contig(vb + (2 * st + 1) * 512 + lrd);        // ch0,pbb
            const short8 v10 = ld_contig(vb + 2048 + (2 * st) * 512 + lrd);     // ch1,pba
            const short8 v11 = ld_contig(vb + 2048 + (2 * st + 1) * 512 + lrd); // ch1,pbb

            // ---- ts=0: softmax + PV ----
            {
                short8 pba, pbb;
                softmax_pack(wA, dsum0, pba, pbb);
                o00 = __builtin_amdgcn_mfma_f32_32x32x16_bf16(v00, pba, o00, 0, 0, 0);
                o00 = __builtin_amdgcn_mfma_f32_32x32x16_bf16(v01, pbb, o00, 0, 0, 0);
                o10 = __builtin_amdgcn_mfma_f32_32x32x16_bf16(v10, pba, o10, 0, 0, 0);
                o10 = __builtin_amdgcn_mfma_f32_32x32x16_bf16(v11, pbb, o10, 0, 0, 0);
            }
            // ---- ts=1: softmax + PV ----
            {
                short8 pba, pbb;
                softmax_pack(wB, dsum1, pba, pbb);
                o01 = __builtin_amdgcn_mfma_f32_32x32x16_bf16(v00, pba, o01, 0, 0, 0);
                o01 = __builtin_amdgcn_mfma_f32_32x32x16_bf16(v01, pbb, o01, 0, 0, 0);
                o11 = __builtin_amdgcn_mfma_f32_32x32x16_bf16(v10, pba, o11, 0, 0, 0);
                o11 = __builtin_amdgcn_mfma_f32_32x32x16_bf16(v11, pbb, o11, 0, 0, 0);
            }
        }
        __builtin_amdgcn_s_setprio(0);
    }

    // ---- denominators: lane pairs (l, l+32) share t, cover complementary s ----
    const float inv0 = 1.0f / (dsum0 + __shfl_xor(dsum0, 32, 64));
    const float inv1 = 1.0f / (dsum1 + __shfl_xor(dsum1, 32, 64));

    // ---- epilogue: D col=t, row=c = 32*ch + (r&3)+8*(r>>2)+4*hi ----
    float* outp = out + (size_t)b * CH_ * T_;
#pragma unroll
    for (int r = 0; r < 16; ++r) {
        const int crow = (r & 3) + 8 * (r >> 2) + 4 * hi;
        float* row0 = outp + (size_t)crow * T_ + tb + l31;
        float* row1 = outp + (size_t)(32 + crow) * T_ + tb + l31;
        row0[0]  = o00[r] * inv0;
        row0[32] = o01[r] * inv1;
        row1[0]  = o10[r] * inv0;
        row1[32] = o11[r] * inv1;
    }
}

// ---------------- fallback (round-1 kernel, used if ws too small) ----------------
__global__ __launch_bounds__(256) void qkv_attn_fb(const float* __restrict__ qkv,
                                                   float* __restrict__ out)
{
    __shared__ unsigned short Qs[CH_][68];
    __shared__ unsigned short Ksf[CH_][68];
    __shared__ unsigned short Vsf[CH_][72];
    __shared__ unsigned short Psf[4][64][18];

    const int tid  = threadIdx.x;
    const int lane = tid & 63;
    const int wid  = tid >> 6;
    const int l15  = lane & 15;
    const int h    = lane >> 4;
    const int bidx = blockIdx.x;
    const int b    = bidx >> 5;
    const int t0   = (bidx & 31) * 64;
    const int tw   = wid * 16;

    const float* Qp = qkv + (size_t)b * (3 * CH_ * T_);
    const float* Kp = Qp + CH_ * T_;
    const float* Vp = Kp + CH_ * T_;

    const int srow = tid >> 4;
    const int scol = (tid & 15) << 2;

#pragma unroll
    for (int i = 0; i < 4; ++i) {
        const int c = srow + 16 * i;
        const float4 q = *(const float4*)(Qp + (size_t)c * T_ + t0 + scol);
        us4 w; w[0] = f2bf(q.x); w[1] = f2bf(q.y); w[2] = f2bf(q.z); w[3] = f2bf(q.w);
        *(us4*)(&Qs[c][scol]) = w;
    }
    __syncthreads();

    const short8 aq0 = ld_strided(&Qs[0 + 8 * h][tw + l15], 68);
    const short8 aq1 = ld_strided(&Qs[32 + 8 * h][tw + l15], 68);

    short8 aones;
#pragma unroll
    for (int j = 0; j < 8; ++j) aones[j] = (short)0x3F80;

    f32x4 o[4];
#pragma unroll
    for (int cs = 0; cs < 4; ++cs) o[cs] = (f32x4){0.f, 0.f, 0.f, 0.f};
    float l_run = 0.0f;
    const f32x4 zero4 = {0.f, 0.f, 0.f, 0.f};

    for (int it = 0; it < 32; ++it) {
        const int s0 = it * 64;
        __syncthreads();
#pragma unroll
        for (int i = 0; i < 4; ++i) {
            const int c = srow + 16 * i;
            const float4 kv = *(const float4*)(Kp + (size_t)c * T_ + s0 + scol);
            us4 wk; wk[0] = f2bf(kv.x); wk[1] = f2bf(kv.y); wk[2] = f2bf(kv.z); wk[3] = f2bf(kv.w);
            *(us4*)(&Ksf[c][scol]) = wk;
            const float4 vv = *(const float4*)(Vp + (size_t)c * T_ + s0 + scol);
            us4 wv; wv[0] = f2bf(vv.x); wv[1] = f2bf(vv.y); wv[2] = f2bf(vv.z); wv[3] = f2bf(vv.w);
            *(us4*)(&Vsf[c][scol]) = wv;
        }
        __syncthreads();

        f32x4 w[4];
#pragma unroll
        for (int ss = 0; ss < 4; ++ss) {
            const short8 bkl = ld_strided(&Ksf[0 + 8 * h][ss * 16 + l15], 68);
            const short8 bkh = ld_strided(&Ksf[32 + 8 * h][ss * 16 + l15], 68);
            f32x4 acc = zero4;
            acc = __builtin_amdgcn_mfma_f32_16x16x32_bf16(aq0, bkl, acc, 0, 0, 0);
            acc = __builtin_amdgcn_mfma_f32_16x16x32_bf16(aq1, bkh, acc, 0, 0, 0);
            w[ss] = acc;
        }

#pragma unroll
        for (int ss = 0; ss < 4; ++ss) {
            const float e0 = __expf(0.125f * w[ss][0]);
            const float e1 = __expf(0.125f * w[ss][1]);
            const float e2 = __expf(0.125f * w[ss][2]);
            const float e3 = __expf(0.125f * w[ss][3]);
            const unsigned p01 = (unsigned)f2bf(e0) | ((unsigned)f2bf(e1) << 16);
            const unsigned p23 = (unsigned)f2bf(e2) | ((unsigned)f2bf(e3) << 16);
            const int s = ss * 16 + l15;
            *(unsigned*)(&Psf[wid][s][4 * h]) = p01;
            *(unsigned*)(&Psf[wid][s][4 * h + 2]) = p23;
        }

        const short8 pb0 = ld_strided(&Psf[wid][0 + 8 * h][l15], 18);
        const short8 pb1 = ld_strided(&Psf[wid][32 + 8 * h][l15], 18);

        f32x4 lacc = zero4;
        lacc = __builtin_amdgcn_mfma_f32_16x16x32_bf16(aones, pb0, lacc, 0, 0, 0);
        lacc = __builtin_amdgcn_mfma_f32_16x16x32_bf16(aones, pb1, lacc, 0, 0, 0);
        l_run += lacc[0];

#pragma unroll
        for (int cs = 0; cs < 4; ++cs) {
            us4 lo0 = *(const us4*)(&Vsf[cs * 16 + l15][0 + 8 * h]);
            us4 hi0 = *(const us4*)(&Vsf[cs * 16 + l15][4 + 8 * h]);
            us4 lo1 = *(const us4*)(&Vsf[cs * 16 + l15][32 + 8 * h]);
            us4 hi1 = *(const us4*)(&Vsf[cs * 16 + l15][36 + 8 * h]);
            short8 av0, av1;
            av0[0]=(short)lo0[0]; av0[1]=(short)lo0[1]; av0[2]=(short)lo0[2]; av0[3]=(short)lo0[3];
            av0[4]=(short)hi0[0]; av0[5]=(short)hi0[1]; av0[6]=(short)hi0[2]; av0[7]=(short)hi0[3];
            av1[0]=(short)lo1[0]; av1[1]=(short)lo1[1]; av1[2]=(short)lo1[2]; av1[3]=(short)lo1[3];
            av1[4]=(short)hi1[0]; av1[5]=(short)hi1[1]; av1[6]=(short)hi1[2]; av1[7]=(short)hi1[3];
            o[cs] = __builtin_amdgcn_mfma_f32_16x16x32_bf16(av0, pb0, o[cs], 0, 0, 0);
            o[cs] = __builtin_amdgcn_mfma_f32_16x16x32_bf16(av1, pb1, o[cs], 0, 0, 0);
        }
    }

    const float invd = 1.0f / l_run;
    float* outp = out + (size_t)b * CH_ * T_;
#pragma unroll
    for (int cs = 0; cs < 4; ++cs)
#pragma unroll
        for (int r = 0; r < 4; ++r)
            outp[(size_t)(cs * 16 + 4 * h + r) * T_ + t0 + tw + l15] = o[cs][r] * invd;
}

extern "C" void kernel_launch(void* const* d_in, const int* in_sizes, int n_in,
                              void* d_out, int out_size, void* d_ws, size_t ws_size,
                              hipStream_t stream) {
    const float* qkv = (const float*)d_in[0];
    float* outp = (float*)d_out;
    const size_t need = (size_t)2 * B_ * CH_ * T_ * sizeof(unsigned short); // 32 MB
    if (ws_size >= need) {
        unsigned short* Ktg = (unsigned short*)d_ws;
        unsigned short* Vbg = Ktg + (size_t)B_ * T_ * CH_;
        qkv_prep<<<dim3(B_ * 32), dim3(256), 0, stream>>>(qkv, Ktg, Vbg);
        qkv_attn17<<<dim3(B_ * (T_ / TQ)), dim3(256), 0, stream>>>(qkv, Ktg, Vbg, outp);
    } else {
        qkv_attn_fb<<<dim3(B_ * 32), dim3(256), 0, stream>>>(qkv, outp);
    }
}